// Round 11
// baseline (34.043 us; speedup 1.0000x reference)
//
#include <hip/hip_runtime.h>

typedef float v2f __attribute__((ext_vector_type(2)));

namespace {
constexpr int kB = 16384;
constexpr int kC = 1000;
constexpr int kNElem = kB * kC;           // 16,384,000
constexpr int kNV4 = kNElem / 4;          // 4,096,000 float4 chunks
constexpr int kV4PerRow = kC / 4;         // 250
constexpr int kBlocks = 2000;             // 512,000 threads: kNV4 / 512,000 = 8 EXACTLY
constexpr int kThreads = 256;
constexpr int kS = kBlocks * kThreads;    // 512,000 (grid stride in float4s)
constexpr int kN = 8;                     // chunks per thread, uniform, no tail
}

// ws: float pf[10][kBlocks] — per-block hinge-sum partials acc_j (c_0 = 0 -> T)
//     u32   pu[10][kBlocks] — per-block bin-count partials N_k
// No global atomics (R8 lesson: same-line atomic RMWs cost ~20 us of drain).
// finalize (f64): cnt_j = sum_{k>=j} N_k; cum_j = acc_j - c_j*(N - cnt_j);
//                 S_k = cum_k - cum_{k+1}; loss = (1/n) sum_{N_k>0} S_k/N_k.

__device__ __forceinline__ void ghmc_elem(float L, float& bce, unsigned& bin)
{
    const float kLn2   = 0.6931471805599453f;
    const float kNRLn2 = -1.4426950408889634f;
    const float en  = __builtin_amdgcn_exp2f(kNRLn2 * fabsf(L));  // e^{-|L|}
    const float den = 1.f + en;
    const float lg  = __builtin_amdgcn_logf(den);                 // log2(den)
    const float r   = __builtin_amdgcn_rcpf(den);
    bce = fmaf(lg, kLn2, fmaxf(L, 0.f));                          // softplus(L)
    unsigned babs = (unsigned)(10.f * r);
    babs = babs > 9u ? 9u : babs;                                 // in [5,9]
    bin = (L >= 0.f) ? babs : 9u - babs;
}

// one float4 chunk (4 consecutive elements of one row) + rare target correction.
__device__ __forceinline__ void proc4(const float4 v, int dt,
    v2f& a01, v2f& a23, v2f& a45, v2f& a67, v2f& a89,
    unsigned long long& hcnt,
    const v2f C01, const v2f C23, const v2f C45, const v2f C67, const v2f C89)
{
    const float lv[4] = {v.x, v.y, v.z, v.w};
    #pragma unroll
    for (int e = 0; e < 4; ++e) {
        float bce; unsigned bin;
        ghmc_elem(lv[e], bce, bin);
        hcnt += 1ull << (6u * bin);
        const v2f b2 = {bce, bce};
        a01 += __builtin_elementwise_max(b2, C01);
        a23 += __builtin_elementwise_max(b2, C23);
        a45 += __builtin_elementwise_max(b2, C45);
        a67 += __builtin_elementwise_max(b2, C67);
        a89 += __builtin_elementwise_max(b2, C89);
    }
    if (__builtin_expect((unsigned)dt < 4u, 0)) {
        float L = v.x;
        L = (dt == 1) ? v.y : L;
        L = (dt == 2) ? v.z : L;
        L = (dt == 3) ? v.w : L;
        float bn_; unsigned bnb;
        ghmc_elem(L, bn_, bnb);                 // what the main path added
        const float bt_ = bn_ - L;              // softplus(-L) = softplus(L) - L
        const unsigned babs = (bnb >= 5u) ? bnb : 9u - bnb;   // |L|-bin in [5,9]
        const unsigned btb  = (L <= 0.f) ? babs : 9u - babs;
        hcnt += (1ull << (6u * btb)) - (1ull << (6u * bnb));
        const v2f bn2 = {bn_, bn_}, bt2 = {bt_, bt_};
        a01 += __builtin_elementwise_max(bt2, C01) - __builtin_elementwise_max(bn2, C01);
        a23 += __builtin_elementwise_max(bt2, C23) - __builtin_elementwise_max(bn2, C23);
        a45 += __builtin_elementwise_max(bt2, C45) - __builtin_elementwise_max(bn2, C45);
        a67 += __builtin_elementwise_max(bt2, C67) - __builtin_elementwise_max(bn2, C67);
        a89 += __builtin_elementwise_max(bt2, C89) - __builtin_elementwise_max(bn2, C89);
    }
}

__global__ __launch_bounds__(kThreads) void ghmc_main(
    const float* __restrict__ logits,
    const int* __restrict__ tgt,
    float* __restrict__ pf,
    unsigned* __restrict__ pu)
{
    const v2f C01 = {0.0f,        0.10536052f};
    const v2f C23 = {0.22314355f, 0.35667494f};
    const v2f C45 = {0.51082562f, 0.69314718f};
    const v2f C67 = {0.91629073f, 1.20397280f};
    const v2f C89 = {1.60943791f, 2.30258509f};

    v2f a01 = {0.f,0.f}, a23 = {0.f,0.f}, a45 = {0.f,0.f},
        a67 = {0.f,0.f}, a89 = {0.f,0.f};
    unsigned long long hcnt = 0ull;

    const int gid = blockIdx.x * kThreads + threadIdx.x;   // 0 .. 511,999
    const float4* __restrict__ Lp = reinterpret_cast<const float4*>(logits);

    // STRAIGHT-LINE, exact division: 8 chunks/thread, no tail, no clamps.
    // All arrays constant-indexed under full unroll -> registers (rule #20 safe).
    float4 q[kN];
    int    dt[kN];

    #pragma unroll
    for (int k = 0; k < 4; ++k) q[k] = Lp[gid + k * kS];   // first 4 data loads
    #pragma unroll
    for (int k = 0; k < kN; ++k) {                         // all 8 tgt loads early
        const int i = gid + k * kS;
        const int row = i / kV4PerRow;                     // magic-mul div
        dt[k] = tgt[row] - (i - row * kV4PerRow) * 4;
    }
    #pragma unroll
    for (int k = 0; k < kN; ++k) {
        if (k < 4) q[k + 4] = Lp[gid + (k + 4) * kS];      // distance-4 prefetch
        proc4(q[k], dt[k], a01, a23, a45, a67, a89, hcnt, C01, C23, C45, C67, C89);
    }

    // expand 6-bit fields -> two u64 with 12-bit fields (wave sum <= 32*64 = 2048 < 4096)
    unsigned long long lo = 0ull, hi = 0ull;
    #pragma unroll
    for (int j = 0; j < 5; ++j) {
        lo += ((hcnt >> (6 * j))       & 63ull) << (12 * j);
        hi += ((hcnt >> (6 * (j + 5))) & 63ull) << (12 * j);
    }
    float r10[10] = {a01.x, a01.y, a23.x, a23.y, a45.x, a45.y, a67.x, a67.y, a89.x, a89.y};
    #pragma unroll
    for (int off = 32; off > 0; off >>= 1) {
        #pragma unroll
        for (int j = 0; j < 10; ++j) r10[j] += __shfl_down(r10[j], off);
        lo += __shfl_down(lo, off);
        hi += __shfl_down(hi, off);
    }

    __shared__ float              sf[4][10];
    __shared__ unsigned long long sc[4][2];
    const int wave = threadIdx.x >> 6;
    const int lane = threadIdx.x & 63;
    if (lane == 0) {
        #pragma unroll
        for (int j = 0; j < 10; ++j) sf[wave][j] = r10[j];
        sc[wave][0] = lo; sc[wave][1] = hi;
    }
    __syncthreads();
    // per-block partials: PLAIN STORES to a private column — zero global atomics
    const int t = threadIdx.x;
    if (t < 10) {
        pf[t * kBlocks + blockIdx.x] = sf[0][t] + sf[1][t] + sf[2][t] + sf[3][t];
    } else if (t < 20) {
        const int b = t - 10;
        const int half = (b < 5) ? 0 : 1;
        const int sh = 12 * (b < 5 ? b : b - 5);
        unsigned s = 0;
        #pragma unroll
        for (int w = 0; w < 4; ++w) s += (unsigned)((sc[w][half] >> sh) & 4095ull);
        pu[b * kBlocks + blockIdx.x] = s;
    }
}

// 10 waves: wave w reduces sum-slot w (f64) and count-slot w (u32), then finalize.
__global__ __launch_bounds__(640) void ghmc_reduce(
    const float* __restrict__ pf,
    const unsigned* __restrict__ pu,
    float* __restrict__ out)
{
    const int wave = threadIdx.x >> 6;
    const int lane = threadIdx.x & 63;

    double   fs = 0.0;
    unsigned cs = 0u;
    #pragma unroll 8
    for (int b = lane; b < kBlocks; b += 64) {      // coalesced column reads
        fs += (double)pf[wave * kBlocks + b];
        cs += pu[wave * kBlocks + b];
    }
    #pragma unroll
    for (int off = 32; off > 0; off >>= 1) {
        fs += __shfl_down(fs, off);
        cs += __shfl_down(cs, off);
    }

    __shared__ double   sF[10];
    __shared__ unsigned sC[10];
    if (lane == 0) { sF[wave] = fs; sC[wave] = cs; }
    __syncthreads();

    if (threadIdx.x == 0) {
        const double cj[10] = {0.0,
            0.10536051565782630, 0.22314355131420976, 0.35667494393873245,
            0.51082562376599072, 0.69314718055994531, 0.91629073187415511,
            1.20397280432593600, 1.60943791243410040, 2.30258509299404570};
        double N[10], cnt[11], cum[11];
        for (int j = 0; j < 10; ++j) N[j] = (double)sC[j];
        cnt[10] = 0.0;
        for (int j = 9; j >= 0; --j) cnt[j] = cnt[j + 1] + N[j];
        cum[10] = 0.0;
        cum[0] = sF[0];                                   // T (c=0 hinge is exact)
        for (int j = 1; j <= 9; ++j)
            cum[j] = sF[j] - cj[j] * ((double)kNElem - cnt[j]);
        double loss = 0.0, n = 0.0;
        for (int j = 0; j < 10; ++j) {
            if (N[j] > 0.0) { n += 1.0; loss += (cum[j] - cum[j + 1]) / N[j]; }
        }
        out[0] = (float)(loss / (n > 1.0 ? n : 1.0));
    }
}

extern "C" void kernel_launch(void* const* d_in, const int* in_sizes, int n_in,
                              void* d_out, int out_size, void* d_ws, size_t ws_size,
                              hipStream_t stream)
{
    const float* logits = (const float*)d_in[0];
    const int*   tgt    = (const int*)d_in[1];
    float*    pf = (float*)d_ws;                                   // 10 x 2000 f32
    unsigned* pu = (unsigned*)((char*)d_ws + 10 * kBlocks * 4);    // 10 x 2000 u32
    ghmc_main<<<kBlocks, kThreads, 0, stream>>>(logits, tgt, pf, pu);
    ghmc_reduce<<<1, 640, 0, stream>>>(pf, pu, (float*)d_out);
}

// Round 12
// 33.383 us; speedup vs baseline: 1.0198x; 1.0198x over previous
//
#include <hip/hip_runtime.h>

typedef float v2f __attribute__((ext_vector_type(2)));

namespace {
constexpr int kB = 16384;
constexpr int kC = 1000;
constexpr int kNElem = kB * kC;           // 16,384,000
constexpr int kNV4 = kNElem / 4;          // 4,096,000 float4 chunks
constexpr int kV4PerRow = kC / 4;         // 250
constexpr int kBlocks = 1280;             // R10-proven: 5 blk/CU, n = 12..13
constexpr int kThreads = 256;
constexpr int kS = kBlocks * kThreads;    // 327,680 (grid stride in float4s)
}

// ws: float pf[10][kBlocks] — per-block hinge-sum partials acc_j (c_0 = 0 -> T)
//     u32   pu[10][kBlocks] — per-block bin-count partials N_k
// No global atomics (R8 lesson). finalize (f64): cnt_j = sum_{k>=j} N_k;
// cum_j = acc_j - c_j*(N - cnt_j); S_k = cum_k - cum_{k+1};
// loss = (1/n) sum_{N_k>0} S_k/N_k.

__device__ __forceinline__ void ghmc_elem(float L, float& bce, unsigned& bin)
{
    const float kLn2   = 0.6931471805599453f;
    const float kNRLn2 = -1.4426950408889634f;
    const float en  = __builtin_amdgcn_exp2f(kNRLn2 * fabsf(L));  // e^{-|L|}
    const float den = 1.f + en;
    const float lg  = __builtin_amdgcn_logf(den);                 // log2(den)
    const float r   = __builtin_amdgcn_rcpf(den);
    bce = fmaf(lg, kLn2, fmaxf(L, 0.f));                          // softplus(L)
    unsigned babs = (unsigned)(10.f * r);
    babs = babs > 9u ? 9u : babs;                                 // in [5,9]
    bin = (L >= 0.f) ? babs : 9u - babs;
}

// one float4 chunk (4 consecutive elements of one row) + rare target correction.
__device__ __forceinline__ void proc4(const float4 v, int dt,
    v2f& a01, v2f& a23, v2f& a45, v2f& a67, v2f& a89,
    unsigned long long& hcnt,
    const v2f C01, const v2f C23, const v2f C45, const v2f C67, const v2f C89)
{
    const float lv[4] = {v.x, v.y, v.z, v.w};
    #pragma unroll
    for (int e = 0; e < 4; ++e) {
        float bce; unsigned bin;
        ghmc_elem(lv[e], bce, bin);
        hcnt += 1ull << (6u * bin);
        const v2f b2 = {bce, bce};
        a01 += __builtin_elementwise_max(b2, C01);
        a23 += __builtin_elementwise_max(b2, C23);
        a45 += __builtin_elementwise_max(b2, C45);
        a67 += __builtin_elementwise_max(b2, C67);
        a89 += __builtin_elementwise_max(b2, C89);
    }
    if (__builtin_expect((unsigned)dt < 4u, 0)) {
        float L = v.x;
        L = (dt == 1) ? v.y : L;
        L = (dt == 2) ? v.z : L;
        L = (dt == 3) ? v.w : L;
        float bn_; unsigned bnb;
        ghmc_elem(L, bn_, bnb);                 // what the main path added
        const float bt_ = bn_ - L;              // softplus(-L) = softplus(L) - L
        const unsigned babs = (bnb >= 5u) ? bnb : 9u - bnb;   // |L|-bin in [5,9]
        const unsigned btb  = (L <= 0.f) ? babs : 9u - babs;
        hcnt += (1ull << (6u * btb)) - (1ull << (6u * bnb));
        const v2f bn2 = {bn_, bn_}, bt2 = {bt_, bt_};
        a01 += __builtin_elementwise_max(bt2, C01) - __builtin_elementwise_max(bn2, C01);
        a23 += __builtin_elementwise_max(bt2, C23) - __builtin_elementwise_max(bn2, C23);
        a45 += __builtin_elementwise_max(bt2, C45) - __builtin_elementwise_max(bn2, C45);
        a67 += __builtin_elementwise_max(bt2, C67) - __builtin_elementwise_max(bn2, C67);
        a89 += __builtin_elementwise_max(bt2, C89) - __builtin_elementwise_max(bn2, C89);
    }
}

__global__ __launch_bounds__(kThreads) void ghmc_main(
    const float* __restrict__ logits,
    const int* __restrict__ tgt,
    float* __restrict__ pf,
    unsigned* __restrict__ pu)
{
    const v2f C01 = {0.0f,        0.10536052f};
    const v2f C23 = {0.22314355f, 0.35667494f};
    const v2f C45 = {0.51082562f, 0.69314718f};
    const v2f C67 = {0.91629073f, 1.20397280f};
    const v2f C89 = {1.60943791f, 2.30258509f};

    v2f a01 = {0.f,0.f}, a23 = {0.f,0.f}, a45 = {0.f,0.f},
        a67 = {0.f,0.f}, a89 = {0.f,0.f};
    unsigned long long hcnt = 0ull;

    const int gid = blockIdx.x * blockDim.x + threadIdx.x;
    const int n = (kNV4 - 1 - gid) / kS + 1;      // 12 or 13 iterations
    const float4* __restrict__ Lp = reinterpret_cast<const float4*>(logits);

    auto ld = [&](int idx) {                      // clamped (over-read harmless)
        idx = idx < kNV4 ? idx : kNV4 - 1;
        return Lp[idx];
    };
    auto dtf = [&](int idx) {                     // clamped tgt lookup
        idx = idx < kNV4 ? idx : kNV4 - 1;
        const int row = idx / kV4PerRow;          // magic-mul div (const 250)
        return tgt[row] - (idx - row * kV4PerRow) * 4;
    };

    // modulo-scheduled pipeline, depth 3-4, unroll-by-4, BOTH streams (q AND dt)
    // in named cyclic registers. Consuming d_k always leaves the newly issued
    // q/d pair in flight -> every s_waitcnt is a counted vmcnt(>0), never a drain
    // (R10's flaw: dt loaded and consumed inside the same body -> vmcnt(0)/iter).
    int i = gid;
    float4 q0 = ld(i), q1 = ld(i + kS), q2 = ld(i + 2 * kS);
    int    d0 = dtf(i), d1 = dtf(i + kS), d2 = dtf(i + 2 * kS);

    int k = 0;
    for (; k + 4 <= n; k += 4) {
        float4 q3 = ld(i + 3 * kS);
        int    d3 = dtf(i + 3 * kS);
        proc4(q0, d0, a01, a23, a45, a67, a89, hcnt, C01, C23, C45, C67, C89);
        q0 = ld(i + 4 * kS);
        d0 = dtf(i + 4 * kS);
        proc4(q1, d1, a01, a23, a45, a67, a89, hcnt, C01, C23, C45, C67, C89);
        q1 = ld(i + 5 * kS);
        d1 = dtf(i + 5 * kS);
        proc4(q2, d2, a01, a23, a45, a67, a89, hcnt, C01, C23, C45, C67, C89);
        q2 = ld(i + 6 * kS);
        d2 = dtf(i + 6 * kS);
        proc4(q3, d3, a01, a23, a45, a67, a89, hcnt, C01, C23, C45, C67, C89);
        i += 4 * kS;
    }
    if (k < n) {                                  // tail: 0 or 1 iteration
        proc4(q0, d0, a01, a23, a45, a67, a89, hcnt, C01, C23, C45, C67, C89);
    }

    // expand 6-bit fields -> two u64 with 12-bit fields (wave sum <= 52*64 = 3328 < 4096)
    unsigned long long lo = 0ull, hi = 0ull;
    #pragma unroll
    for (int j = 0; j < 5; ++j) {
        lo += ((hcnt >> (6 * j))       & 63ull) << (12 * j);
        hi += ((hcnt >> (6 * (j + 5))) & 63ull) << (12 * j);
    }
    float r10[10] = {a01.x, a01.y, a23.x, a23.y, a45.x, a45.y, a67.x, a67.y, a89.x, a89.y};
    #pragma unroll
    for (int off = 32; off > 0; off >>= 1) {
        #pragma unroll
        for (int j = 0; j < 10; ++j) r10[j] += __shfl_down(r10[j], off);
        lo += __shfl_down(lo, off);
        hi += __shfl_down(hi, off);
    }

    __shared__ float              sf[4][10];
    __shared__ unsigned long long sc[4][2];
    const int wave = threadIdx.x >> 6;
    const int lane = threadIdx.x & 63;
    if (lane == 0) {
        #pragma unroll
        for (int j = 0; j < 10; ++j) sf[wave][j] = r10[j];
        sc[wave][0] = lo; sc[wave][1] = hi;
    }
    __syncthreads();
    // per-block partials: PLAIN STORES to a private column — zero global atomics
    const int t = threadIdx.x;
    if (t < 10) {
        pf[t * kBlocks + blockIdx.x] = sf[0][t] + sf[1][t] + sf[2][t] + sf[3][t];
    } else if (t < 20) {
        const int b = t - 10;
        const int half = (b < 5) ? 0 : 1;
        const int sh = 12 * (b < 5 ? b : b - 5);
        unsigned s = 0;
        #pragma unroll
        for (int w = 0; w < 4; ++w) s += (unsigned)((sc[w][half] >> sh) & 4095ull);
        pu[b * kBlocks + blockIdx.x] = s;
    }
}

// 10 waves: wave w reduces sum-slot w (f64) and count-slot w (u32), then finalize.
__global__ __launch_bounds__(640) void ghmc_reduce(
    const float* __restrict__ pf,
    const unsigned* __restrict__ pu,
    float* __restrict__ out)
{
    const int wave = threadIdx.x >> 6;
    const int lane = threadIdx.x & 63;

    double   fs = 0.0;
    unsigned cs = 0u;
    #pragma unroll 8
    for (int b = lane; b < kBlocks; b += 64) {      // coalesced column reads
        fs += (double)pf[wave * kBlocks + b];
        cs += pu[wave * kBlocks + b];
    }
    #pragma unroll
    for (int off = 32; off > 0; off >>= 1) {
        fs += __shfl_down(fs, off);
        cs += __shfl_down(cs, off);
    }

    __shared__ double   sF[10];
    __shared__ unsigned sC[10];
    if (lane == 0) { sF[wave] = fs; sC[wave] = cs; }
    __syncthreads();

    if (threadIdx.x == 0) {
        const double cj[10] = {0.0,
            0.10536051565782630, 0.22314355131420976, 0.35667494393873245,
            0.51082562376599072, 0.69314718055994531, 0.91629073187415511,
            1.20397280432593600, 1.60943791243410040, 2.30258509299404570};
        double N[10], cnt[11], cum[11];
        for (int j = 0; j < 10; ++j) N[j] = (double)sC[j];
        cnt[10] = 0.0;
        for (int j = 9; j >= 0; --j) cnt[j] = cnt[j + 1] + N[j];
        cum[10] = 0.0;
        cum[0] = sF[0];                                   // T (c=0 hinge is exact)
        for (int j = 1; j <= 9; ++j)
            cum[j] = sF[j] - cj[j] * ((double)kNElem - cnt[j]);
        double loss = 0.0, n = 0.0;
        for (int j = 0; j < 10; ++j) {
            if (N[j] > 0.0) { n += 1.0; loss += (cum[j] - cum[j + 1]) / N[j]; }
        }
        out[0] = (float)(loss / (n > 1.0 ? n : 1.0));
    }
}

extern "C" void kernel_launch(void* const* d_in, const int* in_sizes, int n_in,
                              void* d_out, int out_size, void* d_ws, size_t ws_size,
                              hipStream_t stream)
{
    const float* logits = (const float*)d_in[0];
    const int*   tgt    = (const int*)d_in[1];
    float*    pf = (float*)d_ws;                                   // 10 x 1280 f32
    unsigned* pu = (unsigned*)((char*)d_ws + 10 * kBlocks * 4);    // 10 x 1280 u32
    ghmc_main<<<kBlocks, kThreads, 0, stream>>>(logits, tgt, pf, pu);
    ghmc_reduce<<<1, 640, 0, stream>>>(pf, pu, (float*)d_out);
}